// Round 1
// baseline (472.798 us; speedup 1.0000x reference)
//
#include <hip/hip_runtime.h>
#include <math.h>

#define Bsz 4
#define Tsz 2048
#define Csz 1024
#define NH  16
#define HD  64

typedef short bf16x8 __attribute__((ext_vector_type(8)));
typedef float f32x4  __attribute__((ext_vector_type(4)));
typedef unsigned short u16;

__device__ __forceinline__ u16 f2bf(float f) {
    union { float f; unsigned u; } v; v.f = f;
    unsigned r = v.u + 0x7fffu + ((v.u >> 16) & 1u);
    return (u16)(r >> 16);
}

// ---------------- cast fp32 -> bf16 (8 elems/thread) ----------------
__global__ void cast_kernel(const float* __restrict__ src, u16* __restrict__ dst, int n) {
    int i = (blockIdx.x * blockDim.x + threadIdx.x) * 8;
    if (i + 8 <= n) {
        float4 a = *(const float4*)(src + i);
        float4 b = *(const float4*)(src + i + 4);
        bf16x8 o;
        o[0] = (short)f2bf(a.x); o[1] = (short)f2bf(a.y);
        o[2] = (short)f2bf(a.z); o[3] = (short)f2bf(a.w);
        o[4] = (short)f2bf(b.x); o[5] = (short)f2bf(b.y);
        o[6] = (short)f2bf(b.z); o[7] = (short)f2bf(b.w);
        *(bf16x8*)(dst + i) = o;
    } else {
        for (; i < n; i++) dst[i] = f2bf(src[i]);
    }
}

// ---------------- GEMM: C[m,n] = sum_k A[m,k] * B[n,k] ----------------
// A: M x K bf16 row-major; B: N x K bf16 row-major (i.e. x @ W.T form)
// MODE 0: fp32 store to out[m*N+n]
// MODE 1: bf16 store head-split  out[((b*NH+h)*Tsz+t)*HD + d]
// MODE 2: bf16 store V-transpose out[((b*NH+h)*HD+d)*Tsz + t]
#define LDK 40   // padded LDS stride for 32 k-columns (80B, 16B-aligned, 2-way banks)

template<int MODE>
__global__ __launch_bounds__(256, 2)
void gemm_bt(const u16* __restrict__ A, const u16* __restrict__ Bm,
             void* __restrict__ outp, int M, int N, int K) {
    __shared__ u16 sA[128 * LDK];
    __shared__ u16 sB[128 * LDK];
    const int tid  = threadIdx.x;
    const int wave = tid >> 6, lane = tid & 63;
    const int lr = lane & 15, lq = lane >> 4;
    const int m0 = blockIdx.y * 128, n0 = blockIdx.x * 128;
    const int wm = (wave & 1) * 64, wn = (wave >> 1) * 64;

    f32x4 acc[4][4] = {};

    for (int k0 = 0; k0 < K; k0 += 32) {
        __syncthreads();
        #pragma unroll
        for (int c = tid; c < 512; c += 256) {
            int row = c >> 2, kc = (c & 3) * 8;
            *(bf16x8*)(sA + row * LDK + kc) =
                *(const bf16x8*)(A + (size_t)(m0 + row) * K + k0 + kc);
            *(bf16x8*)(sB + row * LDK + kc) =
                *(const bf16x8*)(Bm + (size_t)(n0 + row) * K + k0 + kc);
        }
        __syncthreads();
        bf16x8 af[4], bfv[4];
        #pragma unroll
        for (int f = 0; f < 4; f++)
            af[f] = *(const bf16x8*)(sA + (wm + f * 16 + lr) * LDK + lq * 8);
        #pragma unroll
        for (int f = 0; f < 4; f++)
            bfv[f] = *(const bf16x8*)(sB + (wn + f * 16 + lr) * LDK + lq * 8);
        #pragma unroll
        for (int i = 0; i < 4; i++)
            #pragma unroll
            for (int j = 0; j < 4; j++)
                acc[i][j] = __builtin_amdgcn_mfma_f32_16x16x32_bf16(af[i], bfv[j], acc[i][j], 0, 0, 0);
    }

    // epilogue: C layout col=lane&15, row=quad*4+reg  [verified m89]
    #pragma unroll
    for (int i = 0; i < 4; i++) {
        #pragma unroll
        for (int j = 0; j < 4; j++) {
            #pragma unroll
            for (int r = 0; r < 4; r++) {
                int m = m0 + wm + i * 16 + lq * 4 + r;
                int n = n0 + wn + j * 16 + lr;
                float v = acc[i][j][r];
                if (MODE == 0) {
                    ((float*)outp)[(size_t)m * N + n] = v;
                } else {
                    int b = m >> 11, t = m & (Tsz - 1);   // Tsz = 2048 = 2^11
                    int h = n >> 6, d = n & (HD - 1);
                    u16 bv = f2bf(v);
                    if (MODE == 1)
                        ((u16*)outp)[(((size_t)b * NH + h) * Tsz + t) * HD + d] = bv;
                    else
                        ((u16*)outp)[(((size_t)b * NH + h) * HD + d) * Tsz + t] = bv;
                }
            }
        }
    }
}

// ---------------- flash attention ----------------
// Q,K: [B*NH, T, 64] bf16 ; Vt: [B*NH, 64, T] bf16 ; O: [B, T, C] bf16
#define LDT 72   // padded LDS stride for 64 cols (144B, 16B-aligned, 2-way banks)

__global__ __launch_bounds__(256, 2)
void attn_kernel(const u16* __restrict__ Q, const u16* __restrict__ Kb,
                 const u16* __restrict__ Vt, u16* __restrict__ O) {
    __shared__ u16 sK[64 * LDT];
    __shared__ u16 sV[64 * LDT];
    __shared__ u16 sP[4][16 * LDT];
    const int tid  = threadIdx.x;
    const int wave = tid >> 6, lane = tid & 63;
    const int lr = lane & 15, lq = lane >> 4;
    const int qb = blockIdx.x, bh = blockIdx.y;
    const int t0 = qb * 64;

    const u16* Qp = Q  + (size_t)bh * Tsz * HD;
    const u16* Kp = Kb + (size_t)bh * Tsz * HD;
    const u16* Vp = Vt + (size_t)bh * HD * Tsz;

    // Q fragments (A-operand layout: m=lane&15, k=quad*8+j), held all kernel
    bf16x8 qf0 = *(const bf16x8*)(Qp + (size_t)(t0 + wave * 16 + lr) * HD + lq * 8);
    bf16x8 qf1 = *(const bf16x8*)(Qp + (size_t)(t0 + wave * 16 + lr) * HD + 32 + lq * 8);

    f32x4 accO[4] = {};
    float mrow[4], lrow[4];
    #pragma unroll
    for (int r = 0; r < 4; r++) { mrow[r] = -1e30f; lrow[r] = 0.f; }

    for (int kb = 0; kb <= qb; kb++) {
        __syncthreads();
        #pragma unroll
        for (int c = tid; c < 512; c += 256) {
            int row = c >> 3, dc = (c & 7) * 8;
            *(bf16x8*)(sK + row * LDT + dc) =
                *(const bf16x8*)(Kp + (size_t)(kb * 64 + row) * HD + dc);
            *(bf16x8*)(sV + row * LDT + dc) =
                *(const bf16x8*)(Vp + (size_t)row * Tsz + kb * 64 + dc);
        }
        __syncthreads();

        // S = Q K^T : wave computes 16 q-rows x 64 k-cols
        f32x4 accS[4];
        #pragma unroll
        for (int j = 0; j < 4; j++) {
            bf16x8 b0 = *(const bf16x8*)(sK + (j * 16 + lr) * LDT + lq * 8);
            bf16x8 b1 = *(const bf16x8*)(sK + (j * 16 + lr) * LDT + 32 + lq * 8);
            f32x4 z = {};
            z = __builtin_amdgcn_mfma_f32_16x16x32_bf16(qf0, b0, z, 0, 0, 0);
            z = __builtin_amdgcn_mfma_f32_16x16x32_bf16(qf1, b1, z, 0, 0, 0);
            accS[j] = z;
        }

        // online softmax (rows live across the 16 lanes of each quad)
        const bool diag = (kb == qb);
        #pragma unroll
        for (int r = 0; r < 4; r++) {
            const int rowg = t0 + wave * 16 + lq * 4 + r;
            float s[4];
            float mx = -1e30f;
            #pragma unroll
            for (int j = 0; j < 4; j++) {
                float v = accS[j][r] * 0.125f;   // 1/sqrt(64)
                if (diag) {
                    int colg = kb * 64 + j * 16 + lr;
                    if (colg > rowg) v = -1e30f;
                }
                s[j] = v;
                mx = fmaxf(mx, v);
            }
            #pragma unroll
            for (int off = 1; off < 16; off <<= 1)
                mx = fmaxf(mx, __shfl_xor(mx, off, 64));
            float mnew  = fmaxf(mrow[r], mx);
            float alpha = __expf(mrow[r] - mnew);
            float rs = 0.f;
            #pragma unroll
            for (int j = 0; j < 4; j++) {
                float p = __expf(s[j] - mnew);
                rs += p;
                sP[wave][(lq * 4 + r) * LDT + j * 16 + lr] = f2bf(p);
            }
            #pragma unroll
            for (int off = 1; off < 16; off <<= 1)
                rs += __shfl_xor(rs, off, 64);
            lrow[r] = lrow[r] * alpha + rs;
            mrow[r] = mnew;
            #pragma unroll
            for (int j = 0; j < 4; j++) accO[j][r] *= alpha;
        }

        // O += P V  (P re-read from LDS in A-layout; V B-frags from sVt rows)
        #pragma unroll
        for (int ks = 0; ks < 2; ks++) {
            bf16x8 pf = *(const bf16x8*)(&sP[wave][0] + lr * LDT + ks * 32 + lq * 8);
            #pragma unroll
            for (int j = 0; j < 4; j++) {
                bf16x8 vf = *(const bf16x8*)(sV + (j * 16 + lr) * LDT + ks * 32 + lq * 8);
                accO[j] = __builtin_amdgcn_mfma_f32_16x16x32_bf16(pf, vf, accO[j], 0, 0, 0);
            }
        }
    }

    // write O (bf16) into [B, T, C] layout for the final projection GEMM
    const int b = bh >> 4, h = bh & 15;
    #pragma unroll
    for (int j = 0; j < 4; j++) {
        #pragma unroll
        for (int r = 0; r < 4; r++) {
            int t = t0 + wave * 16 + lq * 4 + r;
            int d = j * 16 + lr;
            O[((size_t)b * Tsz + t) * Csz + h * HD + d] = f2bf(accO[j][r] / lrow[r]);
        }
    }
}

// ---------------- launcher ----------------
extern "C" void kernel_launch(void* const* d_in, const int* in_sizes, int n_in,
                              void* d_out, int out_size, void* d_ws, size_t ws_size,
                              hipStream_t stream) {
    const float* x  = (const float*)d_in[0];
    const float* Wq = (const float*)d_in[1];
    const float* Wk = (const float*)d_in[2];
    const float* Wv = (const float*)d_in[3];
    const float* Wo = (const float*)d_in[4];
    float* out = (float*)d_out;

    const size_t NX = (size_t)Bsz * Tsz * Csz;  // 8388608
    const size_t NW = (size_t)Csz * Csz;        // 1048576

    char* ws = (char*)d_ws;
    u16* xb  = (u16*)ws; ws += NX * 2;
    u16* wqb = (u16*)ws; ws += NW * 2;
    u16* wkb = (u16*)ws; ws += NW * 2;
    u16* wvb = (u16*)ws; ws += NW * 2;
    u16* wob = (u16*)ws; ws += NW * 2;
    u16* qbuf = (u16*)ws; ws += NX * 2;
    u16* kbuf = (u16*)ws; ws += NX * 2;
    u16* vtb  = (u16*)ws; ws += NX * 2;
    u16* abuf = (u16*)ws; ws += NX * 2;   // total ~88 MB

    cast_kernel<<<dim3((unsigned)(NX / 2048)), 256, 0, stream>>>(x,  xb,  (int)NX);
    cast_kernel<<<dim3((unsigned)(NW / 2048)), 256, 0, stream>>>(Wq, wqb, (int)NW);
    cast_kernel<<<dim3((unsigned)(NW / 2048)), 256, 0, stream>>>(Wk, wkb, (int)NW);
    cast_kernel<<<dim3((unsigned)(NW / 2048)), 256, 0, stream>>>(Wv, wvb, (int)NW);
    cast_kernel<<<dim3((unsigned)(NW / 2048)), 256, 0, stream>>>(Wo, wob, (int)NW);

    dim3 gg(Csz / 128, (Bsz * Tsz) / 128);   // (8, 64)
    gemm_bt<1><<<gg, 256, 0, stream>>>(xb, wqb, qbuf, Bsz * Tsz, Csz, Csz);
    gemm_bt<1><<<gg, 256, 0, stream>>>(xb, wkb, kbuf, Bsz * Tsz, Csz, Csz);
    gemm_bt<2><<<gg, 256, 0, stream>>>(xb, wvb, vtb,  Bsz * Tsz, Csz, Csz);

    attn_kernel<<<dim3(Tsz / 64, Bsz * NH), 256, 0, stream>>>(qbuf, kbuf, vtb, abuf);

    gemm_bt<0><<<gg, 256, 0, stream>>>(abuf, wob, out, Bsz * Tsz, Csz, Csz);
}

// Round 2
// 370.418 us; speedup vs baseline: 1.2764x; 1.2764x over previous
//
#include <hip/hip_runtime.h>
#include <math.h>

#define Bsz 4
#define Tsz 2048
#define Csz 1024
#define NH  16
#define HD  64

typedef short bf16x8 __attribute__((ext_vector_type(8)));
typedef float f32x4  __attribute__((ext_vector_type(4)));
typedef unsigned short u16;

typedef const __attribute__((address_space(1))) unsigned int gas_uint;
typedef __attribute__((address_space(3))) unsigned int las_uint;

__device__ __forceinline__ void async_cp16(const u16* g, u16* l) {
    // direct global->LDS, 16B per lane; LDS dest = uniform base + lane*16
    __builtin_amdgcn_global_load_lds((gas_uint*)g, (las_uint*)l, 16, 0, 0);
}

__device__ __forceinline__ u16 f2bf(float f) {
    union { float f; unsigned u; } v; v.f = f;
    unsigned r = v.u + 0x7fffu + ((v.u >> 16) & 1u);
    return (u16)(r >> 16);
}

// ---------------- cast fp32 -> bf16 (8 elems/thread) ----------------
__global__ void cast_kernel(const float* __restrict__ src, u16* __restrict__ dst, int n) {
    int i = (blockIdx.x * blockDim.x + threadIdx.x) * 8;
    if (i + 8 <= n) {
        float4 a = *(const float4*)(src + i);
        float4 b = *(const float4*)(src + i + 4);
        bf16x8 o;
        o[0] = (short)f2bf(a.x); o[1] = (short)f2bf(a.y);
        o[2] = (short)f2bf(a.z); o[3] = (short)f2bf(a.w);
        o[4] = (short)f2bf(b.x); o[5] = (short)f2bf(b.y);
        o[6] = (short)f2bf(b.z); o[7] = (short)f2bf(b.w);
        *(bf16x8*)(dst + i) = o;
    } else {
        for (; i < n; i++) dst[i] = f2bf(src[i]);
    }
}

// ---------------- GEMM: C[m,n] = sum_k A[m,k] * B[n,k] ----------------
// m97 structure: unpadded 128x32 LDS tiles, global_load_lds width=16.
// MODE 0: fp32 store out[m*N+n] (scale applied)
// MODE 1: bf16 store head-split  out[((b*NH+h)*Tsz+t)*HD + d] (scale applied)
// MODE 2: bf16 store V-transpose out[((b*NH+h)*HD+d)*Tsz + t]
template<int MODE>
__global__ __launch_bounds__(256, 2)
void gemm_bt(const u16* __restrict__ A, const u16* __restrict__ Bm,
             void* __restrict__ outp, int M, int N, int K, float scale) {
    __shared__ u16 sA[128 * 32];
    __shared__ u16 sB[128 * 32];
    const int tid  = threadIdx.x;
    const int wave = tid >> 6, lane = tid & 63;
    const int lr = lane & 15, lq = lane >> 4;
    const int m0 = blockIdx.y * 128, n0 = blockIdx.x * 128;
    const int wm = (wave & 1) * 64, wn = (wave >> 1) * 64;

    // staging: wave w covers rows w*32 .. w*32+31 of each tile (2 instrs each)
    const int srow = lane >> 2;            // 0..15
    const int scol = (lane & 3) * 8;       // 0,8,16,24
    const u16* gA = A  + (size_t)(m0 + wave * 32 + srow) * K + scol;
    const u16* gB = Bm + (size_t)(n0 + wave * 32 + srow) * K + scol;
    u16* lA = sA + wave * 1024;
    u16* lB = sB + wave * 1024;

    f32x4 acc[4][4] = {};

    for (int k0 = 0; k0 < K; k0 += 32) {
        __syncthreads();
        async_cp16(gA + k0,                    lA);
        async_cp16(gA + (size_t)16 * K + k0,   lA + 512);
        async_cp16(gB + k0,                    lB);
        async_cp16(gB + (size_t)16 * K + k0,   lB + 512);
        __syncthreads();   // drains vmcnt+lgkmcnt before reads

        bf16x8 af[4], bfv[4];
        #pragma unroll
        for (int f = 0; f < 4; f++)
            af[f]  = *(const bf16x8*)(sA + (wm + f * 16 + lr) * 32 + lq * 8);
        #pragma unroll
        for (int f = 0; f < 4; f++)
            bfv[f] = *(const bf16x8*)(sB + (wn + f * 16 + lr) * 32 + lq * 8);
        #pragma unroll
        for (int i = 0; i < 4; i++)
            #pragma unroll
            for (int j = 0; j < 4; j++)
                acc[i][j] = __builtin_amdgcn_mfma_f32_16x16x32_bf16(af[i], bfv[j], acc[i][j], 0, 0, 0);
    }

    // epilogue: C layout col=lane&15, row=quad*4+reg  [verified m89]
    #pragma unroll
    for (int i = 0; i < 4; i++) {
        #pragma unroll
        for (int j = 0; j < 4; j++) {
            #pragma unroll
            for (int r = 0; r < 4; r++) {
                int m = m0 + wm + i * 16 + lq * 4 + r;
                int n = n0 + wn + j * 16 + lr;
                float v = acc[i][j][r] * scale;
                if (MODE == 0) {
                    ((float*)outp)[(size_t)m * N + n] = v;
                } else {
                    int b = m >> 11, t = m & (Tsz - 1);
                    int h = n >> 6, d = n & (HD - 1);
                    u16 bv = f2bf(v);
                    if (MODE == 1)
                        ((u16*)outp)[(((size_t)b * NH + h) * Tsz + t) * HD + d] = bv;
                    else
                        ((u16*)outp)[(((size_t)b * NH + h) * HD + d) * Tsz + t] = bv;
                }
            }
        }
    }
}

// ---------------- flash attention, paired q-tiles ----------------
// Q pre-scaled by 0.125*log2(e) so softmax runs in exp2.
// Block x handles q-tiles {x, 31-x}: exactly 33 tile-computations per block.
#define LDT 72

__global__ __launch_bounds__(256, 4)
void attn_kernel(const u16* __restrict__ Q, const u16* __restrict__ Kb,
                 const u16* __restrict__ Vt, u16* __restrict__ O) {
    __shared__ u16 sK[64 * LDT];
    __shared__ u16 sV[64 * LDT];
    __shared__ u16 sP[4][16 * LDT];
    const int tid  = threadIdx.x;
    const int wave = tid >> 6, lane = tid & 63;
    const int lr = lane & 15, lq = lane >> 4;
    const int bh = blockIdx.y;
    const int qa = blockIdx.x;           // 0..15  (short tile)
    const int qc = 31 - qa;              // 16..31 (long tile)
    const int ta = qa * 64, tc = qc * 64;

    const u16* Qp = Q  + (size_t)bh * Tsz * HD;
    const u16* Kp = Kb + (size_t)bh * Tsz * HD;
    const u16* Vp = Vt + (size_t)bh * HD * Tsz;

    // Q fragments (A-layout: m=lane&15, k=quad*8+j)
    bf16x8 qfA0 = *(const bf16x8*)(Qp + (size_t)(ta + wave * 16 + lr) * HD + lq * 8);
    bf16x8 qfA1 = *(const bf16x8*)(Qp + (size_t)(ta + wave * 16 + lr) * HD + 32 + lq * 8);
    bf16x8 qfC0 = *(const bf16x8*)(Qp + (size_t)(tc + wave * 16 + lr) * HD + lq * 8);
    bf16x8 qfC1 = *(const bf16x8*)(Qp + (size_t)(tc + wave * 16 + lr) * HD + 32 + lq * 8);

    f32x4 accOA[4] = {}, accOC[4] = {};
    f32x4 accLA = {}, accLC = {};
    float mA[4], mC[4];
    #pragma unroll
    for (int r = 0; r < 4; r++) { mA[r] = -1e30f; mC[r] = -1e30f; }

    bf16x8 ones;
    #pragma unroll
    for (int i = 0; i < 8; i++) ones[i] = (short)0x3F80;  // bf16 1.0

#define PROCESS(T0, QF0, QF1, ACCO, ACCL, MROW)                                      \
    {                                                                                \
        f32x4 accS[4];                                                               \
        _Pragma("unroll")                                                            \
        for (int j = 0; j < 4; j++) {                                                \
            bf16x8 b0 = *(const bf16x8*)(sK + (j * 16 + lr) * LDT + lq * 8);         \
            bf16x8 b1 = *(const bf16x8*)(sK + (j * 16 + lr) * LDT + 32 + lq * 8);    \
            f32x4 z = {};                                                            \
            z = __builtin_amdgcn_mfma_f32_16x16x32_bf16(QF0, b0, z, 0, 0, 0);        \
            z = __builtin_amdgcn_mfma_f32_16x16x32_bf16(QF1, b1, z, 0, 0, 0);        \
            accS[j] = z;                                                             \
        }                                                                            \
        const bool diag = (kb * 64 == (T0));                                         \
        _Pragma("unroll")                                                            \
        for (int r = 0; r < 4; r++) {                                                \
            const int rowg = (T0) + wave * 16 + lq * 4 + r;                          \
            float sv[4]; float mx = -1e30f;                                          \
            _Pragma("unroll")                                                        \
            for (int j = 0; j < 4; j++) {                                            \
                float v = accS[j][r];                                                \
                if (diag && (kb * 64 + j * 16 + lr > rowg)) v = -1e30f;              \
                sv[j] = v; mx = fmaxf(mx, v);                                        \
            }                                                                        \
            mx = fmaxf(mx, __shfl_xor(mx, 1, 64));                                   \
            mx = fmaxf(mx, __shfl_xor(mx, 2, 64));                                   \
            mx = fmaxf(mx, __shfl_xor(mx, 4, 64));                                   \
            mx = fmaxf(mx, __shfl_xor(mx, 8, 64));                                   \
            float mnew  = fmaxf(MROW[r], mx);                                        \
            float alpha = exp2f(MROW[r] - mnew);                                     \
            MROW[r] = mnew;                                                          \
            _Pragma("unroll")                                                        \
            for (int j = 0; j < 4; j++) {                                            \
                float p = exp2f(sv[j] - mnew);                                       \
                sP[wave][(lq * 4 + r) * LDT + j * 16 + lr] = f2bf(p);                \
            }                                                                        \
            ACCL[r] *= alpha;                                                        \
            _Pragma("unroll")                                                        \
            for (int j = 0; j < 4; j++) ACCO[j][r] *= alpha;                         \
        }                                                                            \
        _Pragma("unroll")                                                            \
        for (int ks = 0; ks < 2; ks++) {                                             \
            bf16x8 pf = *(const bf16x8*)(&sP[wave][0] + lr * LDT + ks * 32 + lq * 8);\
            ACCL = __builtin_amdgcn_mfma_f32_16x16x32_bf16(pf, ones, ACCL, 0, 0, 0); \
            _Pragma("unroll")                                                        \
            for (int j = 0; j < 4; j++) {                                            \
                bf16x8 vf = *(const bf16x8*)(sV + (j * 16 + lr) * LDT + ks * 32 + lq * 8); \
                ACCO[j] = __builtin_amdgcn_mfma_f32_16x16x32_bf16(pf, vf, ACCO[j], 0, 0, 0); \
            }                                                                        \
        }                                                                            \
    }

    for (int kb = 0; kb <= qc; kb++) {
        __syncthreads();
        #pragma unroll
        for (int c = tid; c < 512; c += 256) {
            int row = c >> 3, dc = (c & 7) * 8;
            *(bf16x8*)(sK + row * LDT + dc) =
                *(const bf16x8*)(Kp + (size_t)(kb * 64 + row) * HD + dc);
            *(bf16x8*)(sV + row * LDT + dc) =
                *(const bf16x8*)(Vp + (size_t)row * Tsz + kb * 64 + dc);
        }
        __syncthreads();
        if (kb <= qa) PROCESS(ta, qfA0, qfA1, accOA, accLA, mA);
        PROCESS(tc, qfC0, qfC1, accOC, accLC, mC);
    }
#undef PROCESS

    const int b = bh >> 4, h = bh & 15;
    #pragma unroll
    for (int j = 0; j < 4; j++) {
        #pragma unroll
        for (int r = 0; r < 4; r++) {
            int t = wave * 16 + lq * 4 + r;
            int d = j * 16 + lr;
            O[((size_t)b * Tsz + ta + t) * Csz + h * HD + d] = f2bf(accOA[j][r] / accLA[r]);
            O[((size_t)b * Tsz + tc + t) * Csz + h * HD + d] = f2bf(accOC[j][r] / accLC[r]);
        }
    }
}

// ---------------- launcher ----------------
extern "C" void kernel_launch(void* const* d_in, const int* in_sizes, int n_in,
                              void* d_out, int out_size, void* d_ws, size_t ws_size,
                              hipStream_t stream) {
    const float* x  = (const float*)d_in[0];
    const float* Wq = (const float*)d_in[1];
    const float* Wk = (const float*)d_in[2];
    const float* Wv = (const float*)d_in[3];
    const float* Wo = (const float*)d_in[4];
    float* out = (float*)d_out;

    const size_t NX = (size_t)Bsz * Tsz * Csz;  // 8388608
    const size_t NW = (size_t)Csz * Csz;        // 1048576

    char* ws = (char*)d_ws;
    u16* xb   = (u16*)ws; ws += NX * 2;
    u16* wqb  = (u16*)ws; ws += NW * 2;
    u16* wkb  = (u16*)ws; ws += NW * 2;
    u16* wvb  = (u16*)ws; ws += NW * 2;
    u16* wob  = (u16*)ws; ws += NW * 2;
    u16* qbuf = (u16*)ws; ws += NX * 2;
    u16* kbuf = (u16*)ws; ws += NX * 2;
    u16* vtb  = (u16*)ws; ws += NX * 2;
    u16* abuf = (u16*)ws; ws += NX * 2;

    cast_kernel<<<dim3((unsigned)(NX / 2048)), 256, 0, stream>>>(x,  xb,  (int)NX);
    cast_kernel<<<dim3((unsigned)(NW / 2048)), 256, 0, stream>>>(Wq, wqb, (int)NW);
    cast_kernel<<<dim3((unsigned)(NW / 2048)), 256, 0, stream>>>(Wk, wkb, (int)NW);
    cast_kernel<<<dim3((unsigned)(NW / 2048)), 256, 0, stream>>>(Wv, wvb, (int)NW);
    cast_kernel<<<dim3((unsigned)(NW / 2048)), 256, 0, stream>>>(Wo, wob, (int)NW);

    const float qscale = 0.125f * 1.44269504088896340736f;  // 1/sqrt(64) * log2(e)
    dim3 gg(Csz / 128, (Bsz * Tsz) / 128);   // (8, 64)
    gemm_bt<1><<<gg, 256, 0, stream>>>(xb, wqb, qbuf, Bsz * Tsz, Csz, Csz, qscale);
    gemm_bt<1><<<gg, 256, 0, stream>>>(xb, wkb, kbuf, Bsz * Tsz, Csz, Csz, 1.0f);
    gemm_bt<2><<<gg, 256, 0, stream>>>(xb, wvb, vtb,  Bsz * Tsz, Csz, Csz, 1.0f);

    attn_kernel<<<dim3(16, Bsz * NH), 256, 0, stream>>>(qbuf, kbuf, vtb, abuf);

    gemm_bt<0><<<gg, 256, 0, stream>>>(abuf, wob, out, Bsz * Tsz, Csz, Csz, 1.0f);
}